// Round 10
// baseline (341.659 us; speedup 1.0000x reference)
//
#include <hip/hip_runtime.h>
#include <math.h>

#define NTH 256
#define XSTR 59    // XS stride (floats): (12q+27r)%32 all-distinct -> conflict-free MFMA epilogue
#define QHSTR 72   // Q/K/V f16 stride (halves): head h at col h*8 (7+1 pad); 144B rows (16B-aligned)
#define FSTR 224   // FB stride (ushorts); rows 0..24 only (reads clamped)

typedef __attribute__((ext_vector_type(8))) short short8;
typedef __attribute__((ext_vector_type(4))) float f32x4;
typedef _Float16 half2_t __attribute__((ext_vector_type(2)));

__device__ __forceinline__ half2_t as_h2(unsigned int u) {
    return __builtin_bit_cast(half2_t, u);
}

__device__ __forceinline__ unsigned short f2bf(float x) {          // RNE (prep only)
    unsigned int u = __float_as_uint(x);
    return (unsigned short)((u + 0x7FFFu + ((u >> 16) & 1u)) >> 16);
}
__device__ __forceinline__ unsigned short f2bf_t(float x) {        // truncate
    return (unsigned short)(__float_as_uint(x) >> 16);
}
__device__ __forceinline__ float bf2f(unsigned short v) {
    return __uint_as_float(((unsigned int)v) << 16);
}

__host__ __device__ constexpr int pc_(int v) { int c = 0; while (v) { c += v & 1; v >>= 1; } return c; }
__host__ __device__ constexpr int gp_sign(int a, int b) {
    int s = 0; int t = a >> 1;
    while (t) { s += pc_(t & b); t >>= 1; }
    return (s & 1) ? -1 : 1;
}
#define BLADE(i) ((int)((0x76534210u >> ((i) * 4)) & 0xF))

__device__ __forceinline__ float gelu_sig(float z) {
    float E = __expf(-1.702f * z);
    return z / (1.0f + E);
}

// ---------------- weight prep: bf16, transposed (WT[n][k]), zero-padded ----------------
__global__ void prep_weights(const float* __restrict__ Wq, const float* __restrict__ Wk,
                             const float* __restrict__ Wv, const float* __restrict__ Wo,
                             const float* __restrict__ W1, const float* __restrict__ W2,
                             unsigned short* __restrict__ ws, int L)
{
    int idx = blockIdx.x * NTH + threadIdx.x;
    int total1 = L * 16384, total2 = L * 14336, total3 = L * 14336;
    if (idx < total1) {
        int k = idx & 63, n = (idx >> 6) & 63, mat = (idx >> 12) & 3, l = idx >> 14;
        float v = 0.f;
        if (k < 56 && n < 56) {
            const float* W = (mat == 0) ? Wq : (mat == 1) ? Wk : (mat == 2) ? Wv : Wo;
            v = W[l * 3136 + k * 56 + n];
            if (mat == 0) v *= 0.3779644730092272f;  // 1/sqrt(7) folded
        }
        ws[idx] = f2bf(v);
    } else if (idx < total1 + total2) {
        int t = idx - total1;
        int k = t & 63, n = (t >> 6) % 224, l = t / 14336;
        float v = (k < 56) ? W1[l * 12544 + k * 224 + n] : 0.f;
        ws[idx] = f2bf(v);
    } else if (idx < total1 + total2 + total3) {
        int t = idx - total1 - total2;
        int k = t % 224, n = (t / 224) & 63, l = t / 14336;
        float v = (n < 56) ? W2[l * 12544 + k * 56 + n] : 0.f;
        ws[idx] = f2bf(v);
    }
}

__global__ __launch_bounds__(NTH, 7) void nbody_fused(
    const float* __restrict__ nodes, const float* __restrict__ edges,
    const float* __restrict__ src_mask,
    const float* __restrict__ W_in, const float* __restrict__ b_in,
    const float* __restrict__ W_gp, const float* __restrict__ b_gp,
    const float* __restrict__ ln1g, const float* __restrict__ ln1b,
    const float* __restrict__ ln2g, const float* __restrict__ ln2b,
    const float* __restrict__ b1, const float* __restrict__ b2,
    const unsigned short* __restrict__ ws, int L,
    float* __restrict__ out)
{
    __shared__ __align__(16) float XS[25 * XSTR];        // 5900 B residual fp32
    __shared__ __align__(16) unsigned short HB[2304];    // 4608 B h bf16 [32][72], cols56-63 zero
    __shared__ __align__(16) unsigned short UNI[5600];   // 11200 B: QKV-f16 / FB / prologue staging
    __shared__ unsigned short MKB[625];                  // mask bf16

    _Float16* QH = (_Float16*)UNI;                       // [25][QHSTR]
    _Float16* KH = QH + 25 * QHSTR;
    _Float16* VH = KH + 25 * QHSTR;                      // total 5400 ushorts
    unsigned short* FB = UNI;                            // [25][FSTR] bf16 (5600 exactly)
    float* SRCF = XS;                                    // prologue: src staging (600 floats)
    float* KBs = (float*)UNI;                            // prologue: mv staging [25][56]
    float* VBs = KBs + 25 * 56;                          // prologue: gp staging [25][56]

    const int b = blockIdx.x, tid = threadIdx.x;
    const int lane = tid & 63, wid = tid >> 6;
    const int nl = lane & 15, quad = lane >> 4;
    const int col = wid * 16 + nl;                       // matmul output column (0..63)
    const int pcolh = (col / 7) * 8 + col % 7;           // head-padded column (halves)
    const int ln_g = lane >> 3, ln_p = lane & 7;
    const int ln_s = wid + 4 * ln_g;                     // fused-LN row (valid if <25)

    // ---- P0: load src + mask(bf16); zero HB k-pad ----
    for (int t = tid; t < 600; t += NTH) {
        int s = t / 24, r = t % 24;
        SRCF[t] = (s < 5) ? nodes[b * 120 + t] : edges[b * 480 + (s - 5) * 24 + r];
    }
    for (int t = tid; t < 625; t += NTH) MKB[t] = f2bf(src_mask[b * 625 + t]);
    {
        int r = tid >> 3, c = 56 + (tid & 7);
        HB[r * 72 + c] = 0;
    }
    __syncthreads();

    // ---- P1: src_mv -> KBs ----
    for (int t = tid; t < 1400; t += NTH) {
        int s = t / 56, rem = t % 56, n = rem >> 3, i = rem & 7;
        int g = __popc(BLADE(i));
        float acc = (i == 0) ? b_in[n] : 0.0f;
        #pragma unroll
        for (int m = 0; m < 3; m++)
            acc += SRCF[s * 24 + m * 8 + i] * W_in[n * 12 + m * 4 + g];
        KBs[s * 56 + rem] = acc;
    }
    __syncthreads();

    // ---- P2: geometric product -> VBs ----
    for (int t = tid; t < 175; t += NTH) {
        int s = t / 7, n = t % 7;
        float m8[8], g8[8];
        #pragma unroll
        for (int i = 0; i < 8; i++) { m8[i] = KBs[s * 56 + n * 8 + i]; g8[i] = 0.0f; }
        #pragma unroll
        for (int ai = 0; ai < 8; ai++) {
            const int a = BLADE(ai);
            #pragma unroll
            for (int bi = 0; bi < 8; bi++) {
                const int bb = BLADE(bi);
                const int j = BLADE(a ^ bb);
                const int sg = gp_sign(a, bb);
                g8[j] += (sg > 0) ? (m8[ai] * m8[bi]) : (-m8[ai] * m8[bi]);
            }
        }
        #pragma unroll
        for (int j = 0; j < 8; j++) VBs[s * 56 + n * 8 + j] = g8[j];
    }
    __syncthreads();

    // ---- P3: src2 -> XS (overwrites dead src staging) ----
    for (int t = tid; t < 1400; t += NTH) {
        int s = t / 56, rem = t % 56, n = rem >> 3, i = rem & 7;
        int g = __popc(BLADE(i));
        float acc = (i == 0) ? b_gp[n] : 0.0f;
        #pragma unroll
        for (int m = 0; m < 7; m++)
            acc += KBs[s * 56 + m * 8 + i] * W_gp[n * 56 + m * 4 + g];
        #pragma unroll
        for (int m = 0; m < 7; m++)
            acc += VBs[s * 56 + m * 8 + i] * W_gp[n * 56 + (7 + m) * 4 + g];
        XS[s * XSTR + rem] = acc;
    }
    __syncthreads();

    const unsigned short* w1t_all = ws + (size_t)L * 16384;
    const unsigned short* w2t_all = w1t_all + (size_t)L * 14336;

    for (int l = 0; l < L; l++) {
        const float* g1 = ln1g + l * 56; const float* e1 = ln1b + l * 56;
        const float* g2 = ln2g + l * 56; const float* e2 = ln2b + l * 56;

        // ---- fused LN1 (one pass) + zero Q/K head-pads (FB region is dead here) ----
        if (tid < 200) {
            int s = tid >> 3, hh = tid & 7;
            QH[s * QHSTR + hh * 8 + 7] = (_Float16)0.f;
            KH[s * QHSTR + hh * 8 + 7] = (_Float16)0.f;
        }
        {
            float x[7]; float sum = 0.f, sq = 0.f;
            if (ln_s < 25) {
                const float* xp = XS + ln_s * XSTR + ln_p * 7;
                #pragma unroll
                for (int j = 0; j < 7; j++) { x[j] = xp[j]; sum += x[j]; sq += x[j] * x[j]; }
            }
            #pragma unroll
            for (int off = 1; off < 8; off <<= 1) {
                sum += __shfl_xor(sum, off, 64);
                sq  += __shfl_xor(sq,  off, 64);
            }
            if (ln_s < 25) {
                float mean = sum * (1.0f / 56.0f);
                float rs = rsqrtf(sq * (1.0f / 56.0f) - mean * mean + 1e-5f);
                unsigned short* hp = HB + ln_s * 72 + ln_p * 7;
                #pragma unroll
                for (int j = 0; j < 7; j++) {
                    int d = ln_p * 7 + j;
                    hp[j] = f2bf_t((x[j] - mean) * rs * g1[d] + e1[d]);
                }
            }
        }
        __syncthreads();

        // ---- QKV via MFMA; scatter to head-padded f16 ----
        {
            short8 a[2][2];
            #pragma unroll
            for (int mt = 0; mt < 2; mt++)
                #pragma unroll
                for (int ks = 0; ks < 2; ks++)
                    a[mt][ks] = *(const short8*)(HB + (mt * 16 + nl) * 72 + ks * 32 + quad * 8);
            #pragma unroll
            for (int mat = 0; mat < 3; mat++) {
                const unsigned short* bp = ws + (((size_t)(l * 4 + mat)) << 12) + (((size_t)col) << 6) + quad * 8;
                short8 b0 = *(const short8*)(bp);
                short8 b1f = *(const short8*)(bp + 32);
                f32x4 acc0 = {0, 0, 0, 0}, acc1 = {0, 0, 0, 0};
                acc0 = __builtin_amdgcn_mfma_f32_16x16x32_bf16(a[0][0], b0, acc0, 0, 0, 0);
                acc0 = __builtin_amdgcn_mfma_f32_16x16x32_bf16(a[0][1], b1f, acc0, 0, 0, 0);
                acc1 = __builtin_amdgcn_mfma_f32_16x16x32_bf16(a[1][0], b0, acc1, 0, 0, 0);
                acc1 = __builtin_amdgcn_mfma_f32_16x16x32_bf16(a[1][1], b1f, acc1, 0, 0, 0);
                _Float16* dst = (mat == 0) ? QH : (mat == 1) ? KH : VH;
                if (col < 56) {
                    #pragma unroll
                    for (int r = 0; r < 4; r++) {
                        int row0 = quad * 4 + r;
                        dst[row0 * QHSTR + pcolh] = (_Float16)acc0[r];
                        int row1 = 16 + row0;
                        if (row1 < 25) dst[row1 * QHSTR + pcolh] = (_Float16)acc1[r];
                    }
                }
            }
        }
        __syncthreads();

        // ---- attention: online softmax, f16 packed math (fdot2 + pk ops) ----
        if (tid < 200) {
            int s = tid >> 3, hh = tid & 7;
            uint4 Q = *(const uint4*)(QH + s * QHSTR + hh * 8);
            half2_t q0 = as_h2(Q.x), q1 = as_h2(Q.y), q2 = as_h2(Q.z), q3 = as_h2(Q.w);
            float lsum = 0.f;
            half2_t acc0 = {0, 0}, acc1 = {0, 0}, acc2 = {0, 0}, acc3 = {0, 0};
            #pragma unroll 2
            for (int kk = 0; kk < 25; kk++) {
                uint4 K = *(const uint4*)(KH + kk * QHSTR + hh * 8);
                float dot = bf2f(MKB[s * 25 + kk]);
                dot = __builtin_amdgcn_fdot2(q3, as_h2(K.w), dot, false);
                dot = __builtin_amdgcn_fdot2(q2, as_h2(K.z), dot, false);
                dot = __builtin_amdgcn_fdot2(q1, as_h2(K.y), dot, false);
                dot = __builtin_amdgcn_fdot2(q0, as_h2(K.x), dot, false);
                dot = fminf(dot, 60.0f);
                float p = __expf(dot);
                lsum += p;
                uint4 V = *(const uint4*)(VH + kk * QHSTR + hh * 8);
                _Float16 ph = (_Float16)p;
                half2_t p2 = {ph, ph};
                acc0 += p2 * as_h2(V.x); acc1 += p2 * as_h2(V.y);
                acc2 += p2 * as_h2(V.z); acc3 += p2 * as_h2(V.w);
            }
            float inv = 1.0f / lsum;
            unsigned short* op = HB + s * 72 + hh * 7;
            op[0] = f2bf_t((float)acc0.x * inv); op[1] = f2bf_t((float)acc0.y * inv);
            op[2] = f2bf_t((float)acc1.x * inv); op[3] = f2bf_t((float)acc1.y * inv);
            op[4] = f2bf_t((float)acc2.x * inv); op[5] = f2bf_t((float)acc2.y * inv);
            op[6] = f2bf_t((float)acc3.x * inv);
        }
        __syncthreads();

        // ---- x += o @ Wo ----
        {
            short8 a[2][2];
            #pragma unroll
            for (int mt = 0; mt < 2; mt++)
                #pragma unroll
                for (int ks = 0; ks < 2; ks++)
                    a[mt][ks] = *(const short8*)(HB + (mt * 16 + nl) * 72 + ks * 32 + quad * 8);
            const unsigned short* bp = ws + (((size_t)(l * 4 + 3)) << 12) + (((size_t)col) << 6) + quad * 8;
            short8 b0 = *(const short8*)(bp);
            short8 b1f = *(const short8*)(bp + 32);
            f32x4 acc0 = {0, 0, 0, 0}, acc1 = {0, 0, 0, 0};
            acc0 = __builtin_amdgcn_mfma_f32_16x16x32_bf16(a[0][0], b0, acc0, 0, 0, 0);
            acc0 = __builtin_amdgcn_mfma_f32_16x16x32_bf16(a[0][1], b1f, acc0, 0, 0, 0);
            acc1 = __builtin_amdgcn_mfma_f32_16x16x32_bf16(a[1][0], b0, acc1, 0, 0, 0);
            acc1 = __builtin_amdgcn_mfma_f32_16x16x32_bf16(a[1][1], b1f, acc1, 0, 0, 0);
            if (col < 56) {
                #pragma unroll
                for (int r = 0; r < 4; r++) {
                    int row0 = quad * 4 + r;
                    XS[row0 * XSTR + col] += acc0[r];
                    int row1 = 16 + row0;
                    if (row1 < 25) XS[row1 * XSTR + col] += acc1[r];
                }
            }
        }
        __syncthreads();

        // ---- fused LN2 ----
        {
            float x[7]; float sum = 0.f, sq = 0.f;
            if (ln_s < 25) {
                const float* xp = XS + ln_s * XSTR + ln_p * 7;
                #pragma unroll
                for (int j = 0; j < 7; j++) { x[j] = xp[j]; sum += x[j]; sq += x[j] * x[j]; }
            }
            #pragma unroll
            for (int off = 1; off < 8; off <<= 1) {
                sum += __shfl_xor(sum, off, 64);
                sq  += __shfl_xor(sq,  off, 64);
            }
            if (ln_s < 25) {
                float mean = sum * (1.0f / 56.0f);
                float rs = rsqrtf(sq * (1.0f / 56.0f) - mean * mean + 1e-5f);
                unsigned short* hp = HB + ln_s * 72 + ln_p * 7;
                #pragma unroll
                for (int j = 0; j < 7; j++) {
                    int d = ln_p * 7 + j;
                    hp[j] = f2bf_t((x[j] - mean) * rs * g2[d] + e2[d]);
                }
            }
        }
        __syncthreads();

        // ---- FFN1: f = gelu(h @ W1 + b1) -> FB (clobbers QKV-f16, dead) ----
        {
            short8 a[2][2];
            #pragma unroll
            for (int mt = 0; mt < 2; mt++)
                #pragma unroll
                for (int ks = 0; ks < 2; ks++)
                    a[mt][ks] = *(const short8*)(HB + (mt * 16 + nl) * 72 + ks * 32 + quad * 8);
            for (int u = wid; u < 14; u += 4) {
                int c1 = u * 16 + nl;
                const unsigned short* bp = w1t_all + (((size_t)(l * 224 + c1)) << 6) + quad * 8;
                short8 b0 = *(const short8*)(bp);
                short8 b1f = *(const short8*)(bp + 32);
                f32x4 acc0 = {0, 0, 0, 0}, acc1 = {0, 0, 0, 0};
                acc0 = __builtin_amdgcn_mfma_f32_16x16x32_bf16(a[0][0], b0, acc0, 0, 0, 0);
                acc0 = __builtin_amdgcn_mfma_f32_16x16x32_bf16(a[0][1], b1f, acc0, 0, 0, 0);
                acc1 = __builtin_amdgcn_mfma_f32_16x16x32_bf16(a[1][0], b0, acc1, 0, 0, 0);
                acc1 = __builtin_amdgcn_mfma_f32_16x16x32_bf16(a[1][1], b1f, acc1, 0, 0, 0);
                float bias = b1[l * 224 + c1];
                #pragma unroll
                for (int r = 0; r < 4; r++) {
                    int row0 = quad * 4 + r;
                    FB[row0 * FSTR + c1] = f2bf_t(gelu_sig(acc0[r] + bias));
                    int row1 = 16 + row0;
                    if (row1 < 25) FB[row1 * FSTR + c1] = f2bf_t(gelu_sig(acc1[r] + bias));
                }
            }
        }
        __syncthreads();

        // ---- FFN2: x += f @ W2 + b2 (K=224; out-of-range A-rows clamped to 24) ----
        {
            int r1 = 16 + nl; if (r1 > 24) r1 = 24;      // rows >=25 produce discarded C rows
            const unsigned short* a0p = FB + nl * FSTR;
            const unsigned short* a1p = FB + r1 * FSTR;
            const unsigned short* bp0 = w2t_all + ((size_t)(l * 64 + col)) * 224 + quad * 8;
            f32x4 acc0 = {0, 0, 0, 0}, acc1 = {0, 0, 0, 0};
            #pragma unroll
            for (int ks = 0; ks < 7; ks++) {
                short8 bfrag = *(const short8*)(bp0 + ks * 32);
                short8 a0 = *(const short8*)(a0p + ks * 32 + quad * 8);
                short8 a1 = *(const short8*)(a1p + ks * 32 + quad * 8);
                acc0 = __builtin_amdgcn_mfma_f32_16x16x32_bf16(a0, bfrag, acc0, 0, 0, 0);
                acc1 = __builtin_amdgcn_mfma_f32_16x16x32_bf16(a1, bfrag, acc1, 0, 0, 0);
            }
            if (col < 56) {
                float bias = b2[l * 56 + col];
                #pragma unroll
                for (int r = 0; r < 4; r++) {
                    int row0 = quad * 4 + r;
                    XS[row0 * XSTR + col] += acc0[r] + bias;
                    int row1 = 16 + row0;
                    if (row1 < 25) XS[row1 * XSTR + col] += acc1[r] + bias;
                }
            }
        }
        __syncthreads();
    }

    // ---- output ----
    for (int t = tid; t < 40; t += NTH) {
        int s = t >> 3, j = t & 7;
        out[(b * 5 + s) * 8 + j] = XS[s * XSTR + 8 + j];
    }
}

extern "C" void kernel_launch(void* const* d_in, const int* in_sizes, int n_in,
                              void* d_out, int out_size, void* d_ws, size_t ws_size,
                              hipStream_t stream) {
    const float* nodes = (const float*)d_in[0];
    const float* edges = (const float*)d_in[1];
    const float* mask  = (const float*)d_in[2];
    const int B = in_sizes[0] / 120;
    const float* W_in = (const float*)d_in[4];
    const float* b_in = (const float*)d_in[5];
    const float* W_gp = (const float*)d_in[6];
    const float* b_gp = (const float*)d_in[7];
    const float* Wq   = (const float*)d_in[8];
    const float* Wk   = (const float*)d_in[9];
    const float* Wv   = (const float*)d_in[10];
    const float* Wo   = (const float*)d_in[11];
    const float* ln1g = (const float*)d_in[12];
    const float* ln1b = (const float*)d_in[13];
    const float* ln2g = (const float*)d_in[14];
    const float* ln2b = (const float*)d_in[15];
    const float* W1   = (const float*)d_in[16];
    const float* b1   = (const float*)d_in[17];
    const float* W2   = (const float*)d_in[18];
    const float* b2   = (const float*)d_in[19];
    float* out = (float*)d_out;
    const int L = in_sizes[8] / 3136;

    unsigned short* ws16 = (unsigned short*)d_ws;
    int prep_total = L * (16384 + 14336 + 14336);
    hipLaunchKernelGGL(prep_weights, dim3((prep_total + NTH - 1) / NTH), dim3(NTH), 0, stream,
                       Wq, Wk, Wv, Wo, W1, W2, ws16, L);

    hipLaunchKernelGGL(nbody_fused, dim3(B), dim3(NTH), 0, stream,
                       nodes, edges, mask, W_in, b_in, W_gp, b_gp,
                       ln1g, ln1b, ln2g, ln2b, b1, b2, ws16, L, out);
}

// Round 11
// 322.115 us; speedup vs baseline: 1.0607x; 1.0607x over previous
//
#include <hip/hip_runtime.h>
#include <math.h>

#define NTH 256
#define XSTR 60    // XS stride (floats)
#define QHSTR 72   // Q/K/V f16 stride (halves): head h at col h*8 (7+1 pad); 144B rows (16B-aligned)
#define FSTR 232   // FB stride (ushorts); rows 0..24 only (reads clamped)

typedef __attribute__((ext_vector_type(8))) short short8;
typedef __attribute__((ext_vector_type(4))) float f32x4;
typedef _Float16 half2_t __attribute__((ext_vector_type(2)));

__device__ __forceinline__ half2_t as_h2(unsigned int u) {
    return __builtin_bit_cast(half2_t, u);
}

__device__ __forceinline__ unsigned short f2bf(float x) {          // RNE (prep only)
    unsigned int u = __float_as_uint(x);
    return (unsigned short)((u + 0x7FFFu + ((u >> 16) & 1u)) >> 16);
}
__device__ __forceinline__ unsigned short f2bf_t(float x) {        // truncate
    return (unsigned short)(__float_as_uint(x) >> 16);
}
__device__ __forceinline__ float bf2f(unsigned short v) {
    return __uint_as_float(((unsigned int)v) << 16);
}

__host__ __device__ constexpr int pc_(int v) { int c = 0; while (v) { c += v & 1; v >>= 1; } return c; }
__host__ __device__ constexpr int gp_sign(int a, int b) {
    int s = 0; int t = a >> 1;
    while (t) { s += pc_(t & b); t >>= 1; }
    return (s & 1) ? -1 : 1;
}
#define BLADE(i) ((int)((0x76534210u >> ((i) * 4)) & 0xF))

__device__ __forceinline__ float gelu_sig(float z) {
    float E = __expf(-1.702f * z);
    return z / (1.0f + E);
}

// ---------------- weight prep: bf16, transposed (WT[n][k]), zero-padded ----------------
__global__ void prep_weights(const float* __restrict__ Wq, const float* __restrict__ Wk,
                             const float* __restrict__ Wv, const float* __restrict__ Wo,
                             const float* __restrict__ W1, const float* __restrict__ W2,
                             unsigned short* __restrict__ ws, int L)
{
    int idx = blockIdx.x * NTH + threadIdx.x;
    int total1 = L * 16384, total2 = L * 14336, total3 = L * 14336;
    if (idx < total1) {
        int k = idx & 63, n = (idx >> 6) & 63, mat = (idx >> 12) & 3, l = idx >> 14;
        float v = 0.f;
        if (k < 56 && n < 56) {
            const float* W = (mat == 0) ? Wq : (mat == 1) ? Wk : (mat == 2) ? Wv : Wo;
            v = W[l * 3136 + k * 56 + n];
            if (mat == 0) v *= 0.3779644730092272f;  // 1/sqrt(7) folded
        }
        ws[idx] = f2bf(v);
    } else if (idx < total1 + total2) {
        int t = idx - total1;
        int k = t & 63, n = (t >> 6) % 224, l = t / 14336;
        float v = (k < 56) ? W1[l * 12544 + k * 224 + n] : 0.f;
        ws[idx] = f2bf(v);
    } else if (idx < total1 + total2 + total3) {
        int t = idx - total1 - total2;
        int k = t % 224, n = (t / 224) & 63, l = t / 14336;
        float v = (n < 56) ? W2[l * 12544 + k * 56 + n] : 0.f;
        ws[idx] = f2bf(v);
    }
}

__global__ __launch_bounds__(NTH, 4) void nbody_fused(
    const float* __restrict__ nodes, const float* __restrict__ edges,
    const float* __restrict__ src_mask,
    const float* __restrict__ W_in, const float* __restrict__ b_in,
    const float* __restrict__ W_gp, const float* __restrict__ b_gp,
    const float* __restrict__ ln1g, const float* __restrict__ ln1b,
    const float* __restrict__ ln2g, const float* __restrict__ ln2b,
    const float* __restrict__ b1, const float* __restrict__ b2,
    const unsigned short* __restrict__ ws, int L,
    float* __restrict__ out)
{
    __shared__ __align__(16) float XS[25 * XSTR];        // 6000 B residual fp32
    __shared__ __align__(16) unsigned short HB[2304];    // 4608 B h bf16 [32][72], cols56-63 zero
    __shared__ __align__(16) unsigned short UNI[5800];   // 11600 B: QKV-f16 / FB / prologue staging
    __shared__ __align__(16) unsigned short MKB[626];    // mask bf16

    _Float16* QH = (_Float16*)UNI;                       // [25][QHSTR]
    _Float16* KH = QH + 25 * QHSTR;
    _Float16* VH = KH + 25 * QHSTR;                      // total 5400 ushorts
    unsigned short* FB = UNI;                            // [25][FSTR] bf16
    float* SRCF = XS;                                    // prologue: src staging (600 floats)
    float* KBs = (float*)UNI;                            // prologue: mv staging [25][57]
    float* VBs = KBs + 25 * 57;                          // prologue: gp staging [25][57]

    const int b = blockIdx.x, tid = threadIdx.x;
    const int lane = tid & 63, wid = tid >> 6;
    const int nl = lane & 15, quad = lane >> 4;
    const int col = wid * 16 + nl;                       // matmul output column (0..63)
    const int pcolh = (col / 7) * 8 + col % 7;           // head-padded column (halves)
    const int ln_g = lane >> 3, ln_p = lane & 7;
    const int ln_s = wid + 4 * ln_g;                     // fused-LN row (valid if <25)

    // ---- P0: load src + mask(bf16); zero HB k-pad ----
    for (int t = tid; t < 600; t += NTH) {
        int s = t / 24, r = t % 24;
        SRCF[t] = (s < 5) ? nodes[b * 120 + t] : edges[b * 480 + (s - 5) * 24 + r];
    }
    for (int t = tid; t < 625; t += NTH) MKB[t] = f2bf(src_mask[b * 625 + t]);
    {
        int r = tid >> 3, c = 56 + (tid & 7);
        HB[r * 72 + c] = 0;
    }
    __syncthreads();

    // ---- P1: src_mv -> KBs ----
    for (int t = tid; t < 1400; t += NTH) {
        int s = t / 56, rem = t % 56, n = rem >> 3, i = rem & 7;
        int g = __popc(BLADE(i));
        float acc = (i == 0) ? b_in[n] : 0.0f;
        #pragma unroll
        for (int m = 0; m < 3; m++)
            acc += SRCF[s * 24 + m * 8 + i] * W_in[n * 12 + m * 4 + g];
        KBs[s * 57 + rem] = acc;
    }
    __syncthreads();

    // ---- P2: geometric product -> VBs ----
    for (int t = tid; t < 175; t += NTH) {
        int s = t / 7, n = t % 7;
        float m8[8], g8[8];
        #pragma unroll
        for (int i = 0; i < 8; i++) { m8[i] = KBs[s * 57 + n * 8 + i]; g8[i] = 0.0f; }
        #pragma unroll
        for (int ai = 0; ai < 8; ai++) {
            const int a = BLADE(ai);
            #pragma unroll
            for (int bi = 0; bi < 8; bi++) {
                const int bb = BLADE(bi);
                const int j = BLADE(a ^ bb);
                const int sg = gp_sign(a, bb);
                g8[j] += (sg > 0) ? (m8[ai] * m8[bi]) : (-m8[ai] * m8[bi]);
            }
        }
        #pragma unroll
        for (int j = 0; j < 8; j++) VBs[s * 57 + n * 8 + j] = g8[j];
    }
    __syncthreads();

    // ---- P3: src2 -> XS (overwrites dead src staging) ----
    for (int t = tid; t < 1400; t += NTH) {
        int s = t / 56, rem = t % 56, n = rem >> 3, i = rem & 7;
        int g = __popc(BLADE(i));
        float acc = (i == 0) ? b_gp[n] : 0.0f;
        #pragma unroll
        for (int m = 0; m < 7; m++)
            acc += KBs[s * 57 + m * 8 + i] * W_gp[n * 56 + m * 4 + g];
        #pragma unroll
        for (int m = 0; m < 7; m++)
            acc += VBs[s * 57 + m * 8 + i] * W_gp[n * 56 + (7 + m) * 4 + g];
        XS[s * XSTR + rem] = acc;
    }
    __syncthreads();

    const unsigned short* w1t_all = ws + (size_t)L * 16384;
    const unsigned short* w2t_all = w1t_all + (size_t)L * 14336;

    for (int l = 0; l < L; l++) {
        const float* g1 = ln1g + l * 56; const float* e1 = ln1b + l * 56;
        const float* g2 = ln2g + l * 56; const float* e2 = ln2b + l * 56;

        // ---- fused LN1 (one pass) + zero Q/K head-pads (FB region is dead here) ----
        if (tid < 200) {
            int s = tid >> 3, hh = tid & 7;
            QH[s * QHSTR + hh * 8 + 7] = (_Float16)0.f;
            KH[s * QHSTR + hh * 8 + 7] = (_Float16)0.f;
        }
        {
            float x[7]; float sum = 0.f, sq = 0.f;
            if (ln_s < 25) {
                const float* xp = XS + ln_s * XSTR + ln_p * 7;
                #pragma unroll
                for (int j = 0; j < 7; j++) { x[j] = xp[j]; sum += x[j]; sq += x[j] * x[j]; }
            }
            #pragma unroll
            for (int off = 1; off < 8; off <<= 1) {
                sum += __shfl_xor(sum, off, 64);
                sq  += __shfl_xor(sq,  off, 64);
            }
            if (ln_s < 25) {
                float mean = sum * (1.0f / 56.0f);
                float rs = rsqrtf(sq * (1.0f / 56.0f) - mean * mean + 1e-5f);
                unsigned short* hp = HB + ln_s * 72 + ln_p * 7;
                #pragma unroll
                for (int j = 0; j < 7; j++) {
                    int d = ln_p * 7 + j;
                    hp[j] = f2bf_t((x[j] - mean) * rs * g1[d] + e1[d]);
                }
            }
        }
        __syncthreads();

        // ---- QKV via MFMA; scatter to head-padded f16 ----
        {
            short8 a[2][2];
            #pragma unroll
            for (int mt = 0; mt < 2; mt++)
                #pragma unroll
                for (int ks = 0; ks < 2; ks++)
                    a[mt][ks] = *(const short8*)(HB + (mt * 16 + nl) * 72 + ks * 32 + quad * 8);
            #pragma unroll
            for (int mat = 0; mat < 3; mat++) {
                const unsigned short* bp = ws + (((size_t)(l * 4 + mat)) << 12) + (((size_t)col) << 6) + quad * 8;
                short8 b0 = *(const short8*)(bp);
                short8 b1f = *(const short8*)(bp + 32);
                f32x4 acc0 = {0, 0, 0, 0}, acc1 = {0, 0, 0, 0};
                acc0 = __builtin_amdgcn_mfma_f32_16x16x32_bf16(a[0][0], b0, acc0, 0, 0, 0);
                acc0 = __builtin_amdgcn_mfma_f32_16x16x32_bf16(a[0][1], b1f, acc0, 0, 0, 0);
                acc1 = __builtin_amdgcn_mfma_f32_16x16x32_bf16(a[1][0], b0, acc1, 0, 0, 0);
                acc1 = __builtin_amdgcn_mfma_f32_16x16x32_bf16(a[1][1], b1f, acc1, 0, 0, 0);
                _Float16* dst = (mat == 0) ? QH : (mat == 1) ? KH : VH;
                if (col < 56) {
                    #pragma unroll
                    for (int r = 0; r < 4; r++) {
                        int row0 = quad * 4 + r;
                        dst[row0 * QHSTR + pcolh] = (_Float16)acc0[r];
                        int row1 = 16 + row0;
                        if (row1 < 25) dst[row1 * QHSTR + pcolh] = (_Float16)acc1[r];
                    }
                }
            }
        }
        __syncthreads();

        // ---- attention: online softmax, f16 packed math (fdot2 + pk ops) ----
        if (tid < 200) {
            int s = tid >> 3, hh = tid & 7;
            uint4 Q = *(const uint4*)(QH + s * QHSTR + hh * 8);
            half2_t q0 = as_h2(Q.x), q1 = as_h2(Q.y), q2 = as_h2(Q.z), q3 = as_h2(Q.w);
            float lsum = 0.f;
            half2_t acc0 = {0, 0}, acc1 = {0, 0}, acc2 = {0, 0}, acc3 = {0, 0};
            #pragma unroll 2
            for (int kk = 0; kk < 25; kk++) {
                uint4 K = *(const uint4*)(KH + kk * QHSTR + hh * 8);
                float dot = bf2f(MKB[s * 25 + kk]);
                dot = __builtin_amdgcn_fdot2(q3, as_h2(K.w), dot, false);
                dot = __builtin_amdgcn_fdot2(q2, as_h2(K.z), dot, false);
                dot = __builtin_amdgcn_fdot2(q1, as_h2(K.y), dot, false);
                dot = __builtin_amdgcn_fdot2(q0, as_h2(K.x), dot, false);
                dot = fminf(dot, 60.0f);
                float p = __expf(dot);
                lsum += p;
                uint4 V = *(const uint4*)(VH + kk * QHSTR + hh * 8);
                _Float16 ph = (_Float16)p;
                half2_t p2 = {ph, ph};
                acc0 += p2 * as_h2(V.x); acc1 += p2 * as_h2(V.y);
                acc2 += p2 * as_h2(V.z); acc3 += p2 * as_h2(V.w);
            }
            float inv = 1.0f / lsum;
            unsigned short* op = HB + s * 72 + hh * 7;
            op[0] = f2bf_t((float)acc0.x * inv); op[1] = f2bf_t((float)acc0.y * inv);
            op[2] = f2bf_t((float)acc1.x * inv); op[3] = f2bf_t((float)acc1.y * inv);
            op[4] = f2bf_t((float)acc2.x * inv); op[5] = f2bf_t((float)acc2.y * inv);
            op[6] = f2bf_t((float)acc3.x * inv);
        }
        __syncthreads();

        // ---- x += o @ Wo ----
        {
            short8 a[2][2];
            #pragma unroll
            for (int mt = 0; mt < 2; mt++)
                #pragma unroll
                for (int ks = 0; ks < 2; ks++)
                    a[mt][ks] = *(const short8*)(HB + (mt * 16 + nl) * 72 + ks * 32 + quad * 8);
            const unsigned short* bp = ws + (((size_t)(l * 4 + 3)) << 12) + (((size_t)col) << 6) + quad * 8;
            short8 b0 = *(const short8*)(bp);
            short8 b1f = *(const short8*)(bp + 32);
            f32x4 acc0 = {0, 0, 0, 0}, acc1 = {0, 0, 0, 0};
            acc0 = __builtin_amdgcn_mfma_f32_16x16x32_bf16(a[0][0], b0, acc0, 0, 0, 0);
            acc0 = __builtin_amdgcn_mfma_f32_16x16x32_bf16(a[0][1], b1f, acc0, 0, 0, 0);
            acc1 = __builtin_amdgcn_mfma_f32_16x16x32_bf16(a[1][0], b0, acc1, 0, 0, 0);
            acc1 = __builtin_amdgcn_mfma_f32_16x16x32_bf16(a[1][1], b1f, acc1, 0, 0, 0);
            if (col < 56) {
                #pragma unroll
                for (int r = 0; r < 4; r++) {
                    int row0 = quad * 4 + r;
                    XS[row0 * XSTR + col] += acc0[r];
                    int row1 = 16 + row0;
                    if (row1 < 25) XS[row1 * XSTR + col] += acc1[r];
                }
            }
        }
        __syncthreads();

        // ---- fused LN2 ----
        {
            float x[7]; float sum = 0.f, sq = 0.f;
            if (ln_s < 25) {
                const float* xp = XS + ln_s * XSTR + ln_p * 7;
                #pragma unroll
                for (int j = 0; j < 7; j++) { x[j] = xp[j]; sum += x[j]; sq += x[j] * x[j]; }
            }
            #pragma unroll
            for (int off = 1; off < 8; off <<= 1) {
                sum += __shfl_xor(sum, off, 64);
                sq  += __shfl_xor(sq,  off, 64);
            }
            if (ln_s < 25) {
                float mean = sum * (1.0f / 56.0f);
                float rs = rsqrtf(sq * (1.0f / 56.0f) - mean * mean + 1e-5f);
                unsigned short* hp = HB + ln_s * 72 + ln_p * 7;
                #pragma unroll
                for (int j = 0; j < 7; j++) {
                    int d = ln_p * 7 + j;
                    hp[j] = f2bf_t((x[j] - mean) * rs * g2[d] + e2[d]);
                }
            }
        }
        __syncthreads();

        // ---- FFN1: f = gelu(h @ W1 + b1) -> FB (clobbers QKV-f16, dead) ----
        {
            short8 a[2][2];
            #pragma unroll
            for (int mt = 0; mt < 2; mt++)
                #pragma unroll
                for (int ks = 0; ks < 2; ks++)
                    a[mt][ks] = *(const short8*)(HB + (mt * 16 + nl) * 72 + ks * 32 + quad * 8);
            for (int u = wid; u < 14; u += 4) {
                int c1 = u * 16 + nl;
                const unsigned short* bp = w1t_all + (((size_t)(l * 224 + c1)) << 6) + quad * 8;
                short8 b0 = *(const short8*)(bp);
                short8 b1f = *(const short8*)(bp + 32);
                f32x4 acc0 = {0, 0, 0, 0}, acc1 = {0, 0, 0, 0};
                acc0 = __builtin_amdgcn_mfma_f32_16x16x32_bf16(a[0][0], b0, acc0, 0, 0, 0);
                acc0 = __builtin_amdgcn_mfma_f32_16x16x32_bf16(a[0][1], b1f, acc0, 0, 0, 0);
                acc1 = __builtin_amdgcn_mfma_f32_16x16x32_bf16(a[1][0], b0, acc1, 0, 0, 0);
                acc1 = __builtin_amdgcn_mfma_f32_16x16x32_bf16(a[1][1], b1f, acc1, 0, 0, 0);
                float bias = b1[l * 224 + c1];
                #pragma unroll
                for (int r = 0; r < 4; r++) {
                    int row0 = quad * 4 + r;
                    FB[row0 * FSTR + c1] = f2bf_t(gelu_sig(acc0[r] + bias));
                    int row1 = 16 + row0;
                    if (row1 < 25) FB[row1 * FSTR + c1] = f2bf_t(gelu_sig(acc1[r] + bias));
                }
            }
        }
        __syncthreads();

        // ---- FFN2: x += f @ W2 + b2 (K=224; out-of-range A-rows clamped to 24) ----
        {
            int r1 = 16 + nl; if (r1 > 24) r1 = 24;      // rows >=25 produce discarded C rows
            const unsigned short* a0p = FB + nl * FSTR;
            const unsigned short* a1p = FB + r1 * FSTR;
            const unsigned short* bp0 = w2t_all + ((size_t)(l * 64 + col)) * 224 + quad * 8;
            f32x4 acc0 = {0, 0, 0, 0}, acc1 = {0, 0, 0, 0};
            #pragma unroll
            for (int ks = 0; ks < 7; ks++) {
                short8 bfrag = *(const short8*)(bp0 + ks * 32);
                short8 a0 = *(const short8*)(a0p + ks * 32 + quad * 8);
                short8 a1 = *(const short8*)(a1p + ks * 32 + quad * 8);
                acc0 = __builtin_amdgcn_mfma_f32_16x16x32_bf16(a0, bfrag, acc0, 0, 0, 0);
                acc1 = __builtin_amdgcn_mfma_f32_16x16x32_bf16(a1, bfrag, acc1, 0, 0, 0);
            }
            if (col < 56) {
                float bias = b2[l * 56 + col];
                #pragma unroll
                for (int r = 0; r < 4; r++) {
                    int row0 = quad * 4 + r;
                    XS[row0 * XSTR + col] += acc0[r] + bias;
                    int row1 = 16 + row0;
                    if (row1 < 25) XS[row1 * XSTR + col] += acc1[r] + bias;
                }
            }
        }
        __syncthreads();
    }

    // ---- output ----
    for (int t = tid; t < 40; t += NTH) {
        int s = t >> 3, j = t & 7;
        out[(b * 5 + s) * 8 + j] = XS[s * XSTR + 8 + j];
    }
}

extern "C" void kernel_launch(void* const* d_in, const int* in_sizes, int n_in,
                              void* d_out, int out_size, void* d_ws, size_t ws_size,
                              hipStream_t stream) {
    const float* nodes = (const float*)d_in[0];
    const float* edges = (const float*)d_in[1];
    const float* mask  = (const float*)d_in[2];
    const int B = in_sizes[0] / 120;
    const float* W_in = (const float*)d_in[4];
    const float* b_in = (const float*)d_in[5];
    const float* W_gp = (const float*)d_in[6];
    const float* b_gp = (const float*)d_in[7];
    const float* Wq   = (const float*)d_in[8];
    const float* Wk   = (const float*)d_in[9];
    const float* Wv   = (const float*)d_in[10];
    const float* Wo   = (const float*)d_in[11];
    const float* ln1g = (const float*)d_in[12];
    const float* ln1b = (const float*)d_in[13];
    const float* ln2g = (const float*)d_in[14];
    const float* ln2b = (const float*)d_in[15];
    const float* W1   = (const float*)d_in[16];
    const float* b1   = (const float*)d_in[17];
    const float* W2   = (const float*)d_in[18];
    const float* b2   = (const float*)d_in[19];
    float* out = (float*)d_out;
    const int L = in_sizes[8] / 3136;

    unsigned short* ws16 = (unsigned short*)d_ws;
    int prep_total = L * (16384 + 14336 + 14336);
    hipLaunchKernelGGL(prep_weights, dim3((prep_total + NTH - 1) / NTH), dim3(NTH), 0, stream,
                       Wq, Wk, Wv, Wo, W1, W2, ws16, L);

    hipLaunchKernelGGL(nbody_fused, dim3(B), dim3(NTH), 0, stream,
                       nodes, edges, mask, W_in, b_in, W_gp, b_gp,
                       ln1g, ln1b, ln2g, ln2b, b1, b2, ws16, L, out);
}

// Round 12
// 320.535 us; speedup vs baseline: 1.0659x; 1.0049x over previous
//
#include <hip/hip_runtime.h>
#include <math.h>

#define NTH 256
#define XSTR 60    // XS stride (floats)
#define QHSTR 72   // Q/K/V f16 stride (halves): head h at col h*8 (7+1 pad); 144B rows (16B-aligned)
#define FSTR 232   // FB stride (ushorts); rows 0..24 only (reads clamped)

typedef __attribute__((ext_vector_type(8))) short short8;
typedef __attribute__((ext_vector_type(4))) float f32x4;
typedef _Float16 half2_t __attribute__((ext_vector_type(2)));

__device__ __forceinline__ half2_t as_h2(unsigned int u) {
    return __builtin_bit_cast(half2_t, u);
}

__device__ __forceinline__ unsigned short f2bf(float x) {          // RNE (prep only)
    unsigned int u = __float_as_uint(x);
    return (unsigned short)((u + 0x7FFFu + ((u >> 16) & 1u)) >> 16);
}
__device__ __forceinline__ unsigned short f2bf_t(float x) {        // truncate
    return (unsigned short)(__float_as_uint(x) >> 16);
}
__device__ __forceinline__ float bf2f(unsigned short v) {
    return __uint_as_float(((unsigned int)v) << 16);
}

__host__ __device__ constexpr int pc_(int v) { int c = 0; while (v) { c += v & 1; v >>= 1; } return c; }
__host__ __device__ constexpr int gp_sign(int a, int b) {
    int s = 0; int t = a >> 1;
    while (t) { s += pc_(t & b); t >>= 1; }
    return (s & 1) ? -1 : 1;
}
#define BLADE(i) ((int)((0x76534210u >> ((i) * 4)) & 0xF))

__device__ __forceinline__ float gelu_sig(float z) {
    float E = __expf(-1.702f * z);
    return z / (1.0f + E);
}

// ---------------- weight prep: bf16, transposed (WT[n][k]), zero-padded ----------------
__global__ void prep_weights(const float* __restrict__ Wq, const float* __restrict__ Wk,
                             const float* __restrict__ Wv, const float* __restrict__ Wo,
                             const float* __restrict__ W1, const float* __restrict__ W2,
                             unsigned short* __restrict__ ws, int L)
{
    int idx = blockIdx.x * NTH + threadIdx.x;
    int total1 = L * 16384, total2 = L * 14336, total3 = L * 14336;
    if (idx < total1) {
        int k = idx & 63, n = (idx >> 6) & 63, mat = (idx >> 12) & 3, l = idx >> 14;
        float v = 0.f;
        if (k < 56 && n < 56) {
            const float* W = (mat == 0) ? Wq : (mat == 1) ? Wk : (mat == 2) ? Wv : Wo;
            v = W[l * 3136 + k * 56 + n];
            if (mat == 0) v *= 0.3779644730092272f;  // 1/sqrt(7) folded
        }
        ws[idx] = f2bf(v);
    } else if (idx < total1 + total2) {
        int t = idx - total1;
        int k = t & 63, n = (t >> 6) % 224, l = t / 14336;
        float v = (k < 56) ? W1[l * 12544 + k * 224 + n] : 0.f;
        ws[idx] = f2bf(v);
    } else if (idx < total1 + total2 + total3) {
        int t = idx - total1 - total2;
        int k = t % 224, n = (t / 224) & 63, l = t / 14336;
        float v = (n < 56) ? W2[l * 12544 + k * 56 + n] : 0.f;
        ws[idx] = f2bf(v);
    }
}

__global__ __launch_bounds__(NTH, 5) void nbody_fused(
    const float* __restrict__ nodes, const float* __restrict__ edges,
    const float* __restrict__ src_mask,
    const float* __restrict__ W_in, const float* __restrict__ b_in,
    const float* __restrict__ W_gp, const float* __restrict__ b_gp,
    const float* __restrict__ ln1g, const float* __restrict__ ln1b,
    const float* __restrict__ ln2g, const float* __restrict__ ln2b,
    const float* __restrict__ b1, const float* __restrict__ b2,
    const unsigned short* __restrict__ ws, int L,
    float* __restrict__ out)
{
    __shared__ __align__(16) float XS[25 * XSTR];        // 6000 B residual fp32
    __shared__ __align__(16) unsigned short HB[2304];    // 4608 B h bf16 [32][72], cols56-63 zero
    __shared__ __align__(16) unsigned short UNI[5800];   // 11600 B: QKV-f16 / FB / prologue staging
    __shared__ __align__(16) unsigned short MKB[626];    // mask bf16

    _Float16* QH = (_Float16*)UNI;                       // [25][QHSTR]
    _Float16* KH = QH + 25 * QHSTR;
    _Float16* VH = KH + 25 * QHSTR;                      // total 5400 ushorts
    unsigned short* FB = UNI;                            // [25][FSTR] bf16
    float* SRCF = XS;                                    // prologue: src staging (600 floats)
    float* KBs = (float*)UNI;                            // prologue: mv staging [25][57]
    float* VBs = KBs + 25 * 57;                          // prologue: gp staging [25][57]

    const int b = blockIdx.x, tid = threadIdx.x;
    const int lane = tid & 63, wid = tid >> 6;
    const int nl = lane & 15, quad = lane >> 4;
    const int col = wid * 16 + nl;                       // matmul output column (0..63)
    const int pcolh = (col / 7) * 8 + col % 7;           // head-padded column (halves)
    const int ln_g = lane >> 3, ln_p = lane & 7;
    const int ln_s = wid + 4 * ln_g;                     // fused-LN row (valid if <25)

    // ---- P0: load src + mask(bf16); zero HB k-pad ----
    for (int t = tid; t < 600; t += NTH) {
        int s = t / 24, r = t % 24;
        SRCF[t] = (s < 5) ? nodes[b * 120 + t] : edges[b * 480 + (s - 5) * 24 + r];
    }
    for (int t = tid; t < 625; t += NTH) MKB[t] = f2bf(src_mask[b * 625 + t]);
    {
        int r = tid >> 3, c = 56 + (tid & 7);
        HB[r * 72 + c] = 0;
    }
    __syncthreads();

    // ---- P1: src_mv -> KBs ----
    for (int t = tid; t < 1400; t += NTH) {
        int s = t / 56, rem = t % 56, n = rem >> 3, i = rem & 7;
        int g = __popc(BLADE(i));
        float acc = (i == 0) ? b_in[n] : 0.0f;
        #pragma unroll
        for (int m = 0; m < 3; m++)
            acc += SRCF[s * 24 + m * 8 + i] * W_in[n * 12 + m * 4 + g];
        KBs[s * 57 + rem] = acc;
    }
    __syncthreads();

    // ---- P2: geometric product -> VBs ----
    for (int t = tid; t < 175; t += NTH) {
        int s = t / 7, n = t % 7;
        float m8[8], g8[8];
        #pragma unroll
        for (int i = 0; i < 8; i++) { m8[i] = KBs[s * 57 + n * 8 + i]; g8[i] = 0.0f; }
        #pragma unroll
        for (int ai = 0; ai < 8; ai++) {
            const int a = BLADE(ai);
            #pragma unroll
            for (int bi = 0; bi < 8; bi++) {
                const int bb = BLADE(bi);
                const int j = BLADE(a ^ bb);
                const int sg = gp_sign(a, bb);
                g8[j] += (sg > 0) ? (m8[ai] * m8[bi]) : (-m8[ai] * m8[bi]);
            }
        }
        #pragma unroll
        for (int j = 0; j < 8; j++) VBs[s * 57 + n * 8 + j] = g8[j];
    }
    __syncthreads();

    // ---- P3: src2 -> XS (overwrites dead src staging) ----
    for (int t = tid; t < 1400; t += NTH) {
        int s = t / 56, rem = t % 56, n = rem >> 3, i = rem & 7;
        int g = __popc(BLADE(i));
        float acc = (i == 0) ? b_gp[n] : 0.0f;
        #pragma unroll
        for (int m = 0; m < 7; m++)
            acc += KBs[s * 57 + m * 8 + i] * W_gp[n * 56 + m * 4 + g];
        #pragma unroll
        for (int m = 0; m < 7; m++)
            acc += VBs[s * 57 + m * 8 + i] * W_gp[n * 56 + (7 + m) * 4 + g];
        XS[s * XSTR + rem] = acc;
    }
    __syncthreads();

    const unsigned short* w1t_all = ws + (size_t)L * 16384;
    const unsigned short* w2t_all = w1t_all + (size_t)L * 14336;

    for (int l = 0; l < L; l++) {
        const float* g1 = ln1g + l * 56; const float* e1 = ln1b + l * 56;
        const float* g2 = ln2g + l * 56; const float* e2 = ln2b + l * 56;

        // ---- fused LN1 (one pass) + zero Q/K head-pads (FB region is dead here) ----
        if (tid < 200) {
            int s = tid >> 3, hh = tid & 7;
            QH[s * QHSTR + hh * 8 + 7] = (_Float16)0.f;
            KH[s * QHSTR + hh * 8 + 7] = (_Float16)0.f;
        }
        {
            float x[7]; float sum = 0.f, sq = 0.f;
            if (ln_s < 25) {
                const float* xp = XS + ln_s * XSTR + ln_p * 7;
                #pragma unroll
                for (int j = 0; j < 7; j++) { x[j] = xp[j]; sum += x[j]; sq += x[j] * x[j]; }
            }
            #pragma unroll
            for (int off = 1; off < 8; off <<= 1) {
                sum += __shfl_xor(sum, off, 64);
                sq  += __shfl_xor(sq,  off, 64);
            }
            if (ln_s < 25) {
                float mean = sum * (1.0f / 56.0f);
                float rs = rsqrtf(sq * (1.0f / 56.0f) - mean * mean + 1e-5f);
                unsigned short* hp = HB + ln_s * 72 + ln_p * 7;
                #pragma unroll
                for (int j = 0; j < 7; j++) {
                    int d = ln_p * 7 + j;
                    hp[j] = f2bf_t((x[j] - mean) * rs * g1[d] + e1[d]);
                }
            }
        }
        __syncthreads();

        // ---- QKV via MFMA; scatter to head-padded f16 ----
        {
            short8 a[2][2];
            #pragma unroll
            for (int mt = 0; mt < 2; mt++)
                #pragma unroll
                for (int ks = 0; ks < 2; ks++)
                    a[mt][ks] = *(const short8*)(HB + (mt * 16 + nl) * 72 + ks * 32 + quad * 8);
            #pragma unroll
            for (int mat = 0; mat < 3; mat++) {
                const unsigned short* bp = ws + (((size_t)(l * 4 + mat)) << 12) + (((size_t)col) << 6) + quad * 8;
                short8 b0 = *(const short8*)(bp);
                short8 b1f = *(const short8*)(bp + 32);
                f32x4 acc0 = {0, 0, 0, 0}, acc1 = {0, 0, 0, 0};
                acc0 = __builtin_amdgcn_mfma_f32_16x16x32_bf16(a[0][0], b0, acc0, 0, 0, 0);
                acc0 = __builtin_amdgcn_mfma_f32_16x16x32_bf16(a[0][1], b1f, acc0, 0, 0, 0);
                acc1 = __builtin_amdgcn_mfma_f32_16x16x32_bf16(a[1][0], b0, acc1, 0, 0, 0);
                acc1 = __builtin_amdgcn_mfma_f32_16x16x32_bf16(a[1][1], b1f, acc1, 0, 0, 0);
                _Float16* dst = (mat == 0) ? QH : (mat == 1) ? KH : VH;
                if (col < 56) {
                    #pragma unroll
                    for (int r = 0; r < 4; r++) {
                        int row0 = quad * 4 + r;
                        dst[row0 * QHSTR + pcolh] = (_Float16)acc0[r];
                        int row1 = 16 + row0;
                        if (row1 < 25) dst[row1 * QHSTR + pcolh] = (_Float16)acc1[r];
                    }
                }
            }
        }
        __syncthreads();

        // ---- attention: online softmax, f16 packed math (fdot2 + pk ops) ----
        if (tid < 200) {
            int s = tid >> 3, hh = tid & 7;
            uint4 Q = *(const uint4*)(QH + s * QHSTR + hh * 8);
            half2_t q0 = as_h2(Q.x), q1 = as_h2(Q.y), q2 = as_h2(Q.z), q3 = as_h2(Q.w);
            float lsum = 0.f;
            half2_t acc0 = {0, 0}, acc1 = {0, 0}, acc2 = {0, 0}, acc3 = {0, 0};
            #pragma unroll 2
            for (int kk = 0; kk < 25; kk++) {
                uint4 K = *(const uint4*)(KH + kk * QHSTR + hh * 8);
                float dot = bf2f(MKB[s * 25 + kk]);
                dot = __builtin_amdgcn_fdot2(q3, as_h2(K.w), dot, false);
                dot = __builtin_amdgcn_fdot2(q2, as_h2(K.z), dot, false);
                dot = __builtin_amdgcn_fdot2(q1, as_h2(K.y), dot, false);
                dot = __builtin_amdgcn_fdot2(q0, as_h2(K.x), dot, false);
                dot = fminf(dot, 60.0f);
                float p = __expf(dot);
                lsum += p;
                uint4 V = *(const uint4*)(VH + kk * QHSTR + hh * 8);
                _Float16 ph = (_Float16)p;
                half2_t p2 = {ph, ph};
                acc0 += p2 * as_h2(V.x); acc1 += p2 * as_h2(V.y);
                acc2 += p2 * as_h2(V.z); acc3 += p2 * as_h2(V.w);
            }
            float inv = 1.0f / lsum;
            unsigned short* op = HB + s * 72 + hh * 7;
            op[0] = f2bf_t((float)acc0.x * inv); op[1] = f2bf_t((float)acc0.y * inv);
            op[2] = f2bf_t((float)acc1.x * inv); op[3] = f2bf_t((float)acc1.y * inv);
            op[4] = f2bf_t((float)acc2.x * inv); op[5] = f2bf_t((float)acc2.y * inv);
            op[6] = f2bf_t((float)acc3.x * inv);
        }
        __syncthreads();

        // ---- x += o @ Wo ----
        {
            short8 a[2][2];
            #pragma unroll
            for (int mt = 0; mt < 2; mt++)
                #pragma unroll
                for (int ks = 0; ks < 2; ks++)
                    a[mt][ks] = *(const short8*)(HB + (mt * 16 + nl) * 72 + ks * 32 + quad * 8);
            const unsigned short* bp = ws + (((size_t)(l * 4 + 3)) << 12) + (((size_t)col) << 6) + quad * 8;
            short8 b0 = *(const short8*)(bp);
            short8 b1f = *(const short8*)(bp + 32);
            f32x4 acc0 = {0, 0, 0, 0}, acc1 = {0, 0, 0, 0};
            acc0 = __builtin_amdgcn_mfma_f32_16x16x32_bf16(a[0][0], b0, acc0, 0, 0, 0);
            acc0 = __builtin_amdgcn_mfma_f32_16x16x32_bf16(a[0][1], b1f, acc0, 0, 0, 0);
            acc1 = __builtin_amdgcn_mfma_f32_16x16x32_bf16(a[1][0], b0, acc1, 0, 0, 0);
            acc1 = __builtin_amdgcn_mfma_f32_16x16x32_bf16(a[1][1], b1f, acc1, 0, 0, 0);
            if (col < 56) {
                #pragma unroll
                for (int r = 0; r < 4; r++) {
                    int row0 = quad * 4 + r;
                    XS[row0 * XSTR + col] += acc0[r];
                    int row1 = 16 + row0;
                    if (row1 < 25) XS[row1 * XSTR + col] += acc1[r];
                }
            }
        }
        __syncthreads();

        // ---- fused LN2 ----
        {
            float x[7]; float sum = 0.f, sq = 0.f;
            if (ln_s < 25) {
                const float* xp = XS + ln_s * XSTR + ln_p * 7;
                #pragma unroll
                for (int j = 0; j < 7; j++) { x[j] = xp[j]; sum += x[j]; sq += x[j] * x[j]; }
            }
            #pragma unroll
            for (int off = 1; off < 8; off <<= 1) {
                sum += __shfl_xor(sum, off, 64);
                sq  += __shfl_xor(sq,  off, 64);
            }
            if (ln_s < 25) {
                float mean = sum * (1.0f / 56.0f);
                float rs = rsqrtf(sq * (1.0f / 56.0f) - mean * mean + 1e-5f);
                unsigned short* hp = HB + ln_s * 72 + ln_p * 7;
                #pragma unroll
                for (int j = 0; j < 7; j++) {
                    int d = ln_p * 7 + j;
                    hp[j] = f2bf_t((x[j] - mean) * rs * g2[d] + e2[d]);
                }
            }
        }
        __syncthreads();

        // ---- FFN1: f = gelu(h @ W1 + b1) -> FB (clobbers QKV-f16, dead) ----
        {
            short8 a[2][2];
            #pragma unroll
            for (int mt = 0; mt < 2; mt++)
                #pragma unroll
                for (int ks = 0; ks < 2; ks++)
                    a[mt][ks] = *(const short8*)(HB + (mt * 16 + nl) * 72 + ks * 32 + quad * 8);
            for (int u = wid; u < 14; u += 4) {
                int c1 = u * 16 + nl;
                const unsigned short* bp = w1t_all + (((size_t)(l * 224 + c1)) << 6) + quad * 8;
                short8 b0 = *(const short8*)(bp);
                short8 b1f = *(const short8*)(bp + 32);
                f32x4 acc0 = {0, 0, 0, 0}, acc1 = {0, 0, 0, 0};
                acc0 = __builtin_amdgcn_mfma_f32_16x16x32_bf16(a[0][0], b0, acc0, 0, 0, 0);
                acc0 = __builtin_amdgcn_mfma_f32_16x16x32_bf16(a[0][1], b1f, acc0, 0, 0, 0);
                acc1 = __builtin_amdgcn_mfma_f32_16x16x32_bf16(a[1][0], b0, acc1, 0, 0, 0);
                acc1 = __builtin_amdgcn_mfma_f32_16x16x32_bf16(a[1][1], b1f, acc1, 0, 0, 0);
                float bias = b1[l * 224 + c1];
                #pragma unroll
                for (int r = 0; r < 4; r++) {
                    int row0 = quad * 4 + r;
                    FB[row0 * FSTR + c1] = f2bf_t(gelu_sig(acc0[r] + bias));
                    int row1 = 16 + row0;
                    if (row1 < 25) FB[row1 * FSTR + c1] = f2bf_t(gelu_sig(acc1[r] + bias));
                }
            }
        }
        __syncthreads();

        // ---- FFN2: x += f @ W2 + b2 (K=224; out-of-range A-rows clamped to 24) ----
        {
            int r1 = 16 + nl; if (r1 > 24) r1 = 24;      // rows >=25 produce discarded C rows
            const unsigned short* a0p = FB + nl * FSTR;
            const unsigned short* a1p = FB + r1 * FSTR;
            const unsigned short* bp0 = w2t_all + ((size_t)(l * 64 + col)) * 224 + quad * 8;
            f32x4 acc0 = {0, 0, 0, 0}, acc1 = {0, 0, 0, 0};
            #pragma unroll
            for (int ks = 0; ks < 7; ks++) {
                short8 bfrag = *(const short8*)(bp0 + ks * 32);
                short8 a0 = *(const short8*)(a0p + ks * 32 + quad * 8);
                short8 a1 = *(const short8*)(a1p + ks * 32 + quad * 8);
                acc0 = __builtin_amdgcn_mfma_f32_16x16x32_bf16(a0, bfrag, acc0, 0, 0, 0);
                acc1 = __builtin_amdgcn_mfma_f32_16x16x32_bf16(a1, bfrag, acc1, 0, 0, 0);
            }
            if (col < 56) {
                float bias = b2[l * 56 + col];
                #pragma unroll
                for (int r = 0; r < 4; r++) {
                    int row0 = quad * 4 + r;
                    XS[row0 * XSTR + col] += acc0[r] + bias;
                    int row1 = 16 + row0;
                    if (row1 < 25) XS[row1 * XSTR + col] += acc1[r] + bias;
                }
            }
        }
        __syncthreads();
    }

    // ---- output ----
    for (int t = tid; t < 40; t += NTH) {
        int s = t >> 3, j = t & 7;
        out[(b * 5 + s) * 8 + j] = XS[s * XSTR + 8 + j];
    }
}

extern "C" void kernel_launch(void* const* d_in, const int* in_sizes, int n_in,
                              void* d_out, int out_size, void* d_ws, size_t ws_size,
                              hipStream_t stream) {
    const float* nodes = (const float*)d_in[0];
    const float* edges = (const float*)d_in[1];
    const float* mask  = (const float*)d_in[2];
    const int B = in_sizes[0] / 120;
    const float* W_in = (const float*)d_in[4];
    const float* b_in = (const float*)d_in[5];
    const float* W_gp = (const float*)d_in[6];
    const float* b_gp = (const float*)d_in[7];
    const float* Wq   = (const float*)d_in[8];
    const float* Wk   = (const float*)d_in[9];
    const float* Wv   = (const float*)d_in[10];
    const float* Wo   = (const float*)d_in[11];
    const float* ln1g = (const float*)d_in[12];
    const float* ln1b = (const float*)d_in[13];
    const float* ln2g = (const float*)d_in[14];
    const float* ln2b = (const float*)d_in[15];
    const float* W1   = (const float*)d_in[16];
    const float* b1   = (const float*)d_in[17];
    const float* W2   = (const float*)d_in[18];
    const float* b2   = (const float*)d_in[19];
    float* out = (float*)d_out;
    const int L = in_sizes[8] / 3136;

    unsigned short* ws16 = (unsigned short*)d_ws;
    int prep_total = L * (16384 + 14336 + 14336);
    hipLaunchKernelGGL(prep_weights, dim3((prep_total + NTH - 1) / NTH), dim3(NTH), 0, stream,
                       Wq, Wk, Wv, Wo, W1, W2, ws16, L);

    hipLaunchKernelGGL(nbody_fused, dim3(B), dim3(NTH), 0, stream,
                       nodes, edges, mask, W_in, b_in, W_gp, b_gp,
                       ln1g, ln1b, ln2g, ln2b, b1, b2, ws16, L, out);
}

// Round 13
// 310.756 us; speedup vs baseline: 1.0994x; 1.0315x over previous
//
#include <hip/hip_runtime.h>
#include <math.h>

#define NTH 256
#define XSTR 60    // XS stride (floats)
#define QHSTR 72   // Q/K/V f16 stride (halves): head h at col h*8 (7+1 pad); 144B rows (16B-aligned)
#define FSTR 232   // FB stride (ushorts); rows 0..24 only (reads clamped)
#define LOG2E 1.4426950408889634f

typedef __attribute__((ext_vector_type(8))) short short8;
typedef __attribute__((ext_vector_type(4))) float f32x4;
typedef _Float16 half2_t __attribute__((ext_vector_type(2)));

__device__ __forceinline__ half2_t as_h2(unsigned int u) {
    return __builtin_bit_cast(half2_t, u);
}

__device__ __forceinline__ float fast_exp2(float x) {   // v_exp_f32 is base-2; CDNA VALU fully interlocked
    float r;
    asm("v_exp_f32 %0, %1" : "=v"(r) : "v"(x));
    return r;
}

__device__ __forceinline__ unsigned short f2bf(float x) {          // RNE (prep only)
    unsigned int u = __float_as_uint(x);
    return (unsigned short)((u + 0x7FFFu + ((u >> 16) & 1u)) >> 16);
}
__device__ __forceinline__ unsigned short f2bf_t(float x) {        // truncate
    return (unsigned short)(__float_as_uint(x) >> 16);
}

__host__ __device__ constexpr int pc_(int v) { int c = 0; while (v) { c += v & 1; v >>= 1; } return c; }
__host__ __device__ constexpr int gp_sign(int a, int b) {
    int s = 0; int t = a >> 1;
    while (t) { s += pc_(t & b); t >>= 1; }
    return (s & 1) ? -1 : 1;
}
#define BLADE(i) ((int)((0x76534210u >> ((i) * 4)) & 0xF))

__device__ __forceinline__ float gelu_sig(float z) {
    // z * sigmoid(1.702 z) = z / (1 + exp2(-1.702*log2e*z)); rcp+exp2 fast path
    float E = fast_exp2(-2.4554669f * z);
    return z * __builtin_amdgcn_rcpf(1.0f + E);
}

// ---------------- weight prep: bf16, transposed (WT[n][k]), zero-padded ----------------
__global__ void prep_weights(const float* __restrict__ Wq, const float* __restrict__ Wk,
                             const float* __restrict__ Wv, const float* __restrict__ Wo,
                             const float* __restrict__ W1, const float* __restrict__ W2,
                             unsigned short* __restrict__ ws, int L)
{
    int idx = blockIdx.x * NTH + threadIdx.x;
    int total1 = L * 16384, total2 = L * 14336, total3 = L * 14336;
    if (idx < total1) {
        int k = idx & 63, n = (idx >> 6) & 63, mat = (idx >> 12) & 3, l = idx >> 14;
        float v = 0.f;
        if (k < 56 && n < 56) {
            const float* W = (mat == 0) ? Wq : (mat == 1) ? Wk : (mat == 2) ? Wv : Wo;
            v = W[l * 3136 + k * 56 + n];
            if (mat == 0) v *= 0.3779644730092272f * LOG2E;  // 1/sqrt(7) and log2e folded
        }
        ws[idx] = f2bf(v);
    } else if (idx < total1 + total2) {
        int t = idx - total1;
        int k = t & 63, n = (t >> 6) % 224, l = t / 14336;
        float v = (k < 56) ? W1[l * 12544 + k * 224 + n] : 0.f;
        ws[idx] = f2bf(v);
    } else if (idx < total1 + total2 + total3) {
        int t = idx - total1 - total2;
        int k = t % 224, n = (t / 224) & 63, l = t / 14336;
        float v = (n < 56) ? W2[l * 12544 + k * 56 + n] : 0.f;
        ws[idx] = f2bf(v);
    }
}

__global__ __launch_bounds__(NTH, 5) void nbody_fused(
    const float* __restrict__ nodes, const float* __restrict__ edges,
    const float* __restrict__ src_mask,
    const float* __restrict__ W_in, const float* __restrict__ b_in,
    const float* __restrict__ W_gp, const float* __restrict__ b_gp,
    const float* __restrict__ ln1g, const float* __restrict__ ln1b,
    const float* __restrict__ ln2g, const float* __restrict__ ln2b,
    const float* __restrict__ b1, const float* __restrict__ b2,
    const unsigned short* __restrict__ ws, int L,
    float* __restrict__ out)
{
    __shared__ __align__(16) float XS[25 * XSTR];        // 6000 B residual fp32
    __shared__ __align__(16) unsigned short HB[2304];    // 4608 B h bf16 [32][72], cols56-63 zero
    __shared__ __align__(16) unsigned short UNI[5800];   // 11600 B: QKV-f16 / FB / prologue staging
    __shared__ __align__(16) float MKF[625];             // mask fp32, pre-scaled by log2e

    _Float16* QH = (_Float16*)UNI;                       // [25][QHSTR]
    _Float16* KH = QH + 25 * QHSTR;
    _Float16* VH = KH + 25 * QHSTR;                      // total 5400 ushorts
    unsigned short* FB = UNI;                            // [25][FSTR] bf16
    float* SRCF = XS;                                    // prologue: src staging (600 floats)
    float* KBs = (float*)UNI;                            // prologue: mv staging [25][57]
    float* VBs = KBs + 25 * 57;                          // prologue: gp staging [25][57]

    const int b = blockIdx.x, tid = threadIdx.x;
    const int lane = tid & 63, wid = tid >> 6;
    const int nl = lane & 15, quad = lane >> 4;
    const int col = wid * 16 + nl;                       // matmul output column (0..63)
    const int pcolh = (col / 7) * 8 + col % 7;           // head-padded column (halves)
    const int ln_g = lane >> 3, ln_p = lane & 7;
    const int ln_s = wid + 4 * ln_g;                     // fused-LN row (valid if <25)

    // ---- P0: load src + mask(f32, pre-scaled); zero HB k-pad ----
    for (int t = tid; t < 600; t += NTH) {
        int s = t / 24, r = t % 24;
        SRCF[t] = (s < 5) ? nodes[b * 120 + t] : edges[b * 480 + (s - 5) * 24 + r];
    }
    for (int t = tid; t < 625; t += NTH) MKF[t] = src_mask[b * 625 + t] * LOG2E;
    {
        int r = tid >> 3, c = 56 + (tid & 7);
        HB[r * 72 + c] = 0;
    }
    __syncthreads();

    // ---- P1: src_mv -> KBs ----
    for (int t = tid; t < 1400; t += NTH) {
        int s = t / 56, rem = t % 56, n = rem >> 3, i = rem & 7;
        int g = __popc(BLADE(i));
        float acc = (i == 0) ? b_in[n] : 0.0f;
        #pragma unroll
        for (int m = 0; m < 3; m++)
            acc += SRCF[s * 24 + m * 8 + i] * W_in[n * 12 + m * 4 + g];
        KBs[s * 57 + rem] = acc;
    }
    __syncthreads();

    // ---- P2: geometric product -> VBs ----
    for (int t = tid; t < 175; t += NTH) {
        int s = t / 7, n = t % 7;
        float m8[8], g8[8];
        #pragma unroll
        for (int i = 0; i < 8; i++) { m8[i] = KBs[s * 57 + n * 8 + i]; g8[i] = 0.0f; }
        #pragma unroll
        for (int ai = 0; ai < 8; ai++) {
            const int a = BLADE(ai);
            #pragma unroll
            for (int bi = 0; bi < 8; bi++) {
                const int bb = BLADE(bi);
                const int j = BLADE(a ^ bb);
                const int sg = gp_sign(a, bb);
                g8[j] += (sg > 0) ? (m8[ai] * m8[bi]) : (-m8[ai] * m8[bi]);
            }
        }
        #pragma unroll
        for (int j = 0; j < 8; j++) VBs[s * 57 + n * 8 + j] = g8[j];
    }
    __syncthreads();

    // ---- P3: src2 -> XS (overwrites dead src staging) ----
    for (int t = tid; t < 1400; t += NTH) {
        int s = t / 56, rem = t % 56, n = rem >> 3, i = rem & 7;
        int g = __popc(BLADE(i));
        float acc = (i == 0) ? b_gp[n] : 0.0f;
        #pragma unroll
        for (int m = 0; m < 7; m++)
            acc += KBs[s * 57 + m * 8 + i] * W_gp[n * 56 + m * 4 + g];
        #pragma unroll
        for (int m = 0; m < 7; m++)
            acc += VBs[s * 57 + m * 8 + i] * W_gp[n * 56 + (7 + m) * 4 + g];
        XS[s * XSTR + rem] = acc;
    }
    __syncthreads();

    const unsigned short* w1t_all = ws + (size_t)L * 16384;
    const unsigned short* w2t_all = w1t_all + (size_t)L * 14336;

    for (int l = 0; l < L; l++) {
        const float* g1 = ln1g + l * 56; const float* e1 = ln1b + l * 56;
        const float* g2 = ln2g + l * 56; const float* e2 = ln2b + l * 56;

        // ---- fused LN1 (one pass) + zero Q/K head-pads (FB region is dead here) ----
        if (tid < 200) {
            int s = tid >> 3, hh = tid & 7;
            QH[s * QHSTR + hh * 8 + 7] = (_Float16)0.f;
            KH[s * QHSTR + hh * 8 + 7] = (_Float16)0.f;
        }
        {
            float x[7]; float sum = 0.f, sq = 0.f;
            if (ln_s < 25) {
                const float* xp = XS + ln_s * XSTR + ln_p * 7;
                #pragma unroll
                for (int j = 0; j < 7; j++) { x[j] = xp[j]; sum += x[j]; sq += x[j] * x[j]; }
            }
            #pragma unroll
            for (int off = 1; off < 8; off <<= 1) {
                sum += __shfl_xor(sum, off, 64);
                sq  += __shfl_xor(sq,  off, 64);
            }
            if (ln_s < 25) {
                float mean = sum * (1.0f / 56.0f);
                float rs = __builtin_amdgcn_rsqf(sq * (1.0f / 56.0f) - mean * mean + 1e-5f);
                unsigned short* hp = HB + ln_s * 72 + ln_p * 7;
                #pragma unroll
                for (int j = 0; j < 7; j++) {
                    int d = ln_p * 7 + j;
                    hp[j] = f2bf_t((x[j] - mean) * rs * g1[d] + e1[d]);
                }
            }
        }
        __syncthreads();

        // ---- QKV via MFMA; scatter to head-padded f16 ----
        {
            short8 a[2][2];
            #pragma unroll
            for (int mt = 0; mt < 2; mt++)
                #pragma unroll
                for (int ks = 0; ks < 2; ks++)
                    a[mt][ks] = *(const short8*)(HB + (mt * 16 + nl) * 72 + ks * 32 + quad * 8);
            #pragma unroll
            for (int mat = 0; mat < 3; mat++) {
                const unsigned short* bp = ws + (((size_t)(l * 4 + mat)) << 12) + (((size_t)col) << 6) + quad * 8;
                short8 b0 = *(const short8*)(bp);
                short8 b1f = *(const short8*)(bp + 32);
                f32x4 acc0 = {0, 0, 0, 0}, acc1 = {0, 0, 0, 0};
                acc0 = __builtin_amdgcn_mfma_f32_16x16x32_bf16(a[0][0], b0, acc0, 0, 0, 0);
                acc0 = __builtin_amdgcn_mfma_f32_16x16x32_bf16(a[0][1], b1f, acc0, 0, 0, 0);
                acc1 = __builtin_amdgcn_mfma_f32_16x16x32_bf16(a[1][0], b0, acc1, 0, 0, 0);
                acc1 = __builtin_amdgcn_mfma_f32_16x16x32_bf16(a[1][1], b1f, acc1, 0, 0, 0);
                _Float16* dst = (mat == 0) ? QH : (mat == 1) ? KH : VH;
                if (col < 56) {
                    #pragma unroll
                    for (int r = 0; r < 4; r++) {
                        int row0 = quad * 4 + r;
                        dst[row0 * QHSTR + pcolh] = (_Float16)acc0[r];
                        int row1 = 16 + row0;
                        if (row1 < 25) dst[row1 * QHSTR + pcolh] = (_Float16)acc1[r];
                    }
                }
            }
        }
        __syncthreads();

        // ---- attention: online softmax; q pre-scaled by log2e -> p = v_exp(dot) ----
        if (tid < 200) {
            int s = tid >> 3, hh = tid & 7;
            uint4 Q = *(const uint4*)(QH + s * QHSTR + hh * 8);
            half2_t q0 = as_h2(Q.x), q1 = as_h2(Q.y), q2 = as_h2(Q.z), q3 = as_h2(Q.w);
            float lsum = 0.f;
            half2_t acc0 = {0, 0}, acc1 = {0, 0}, acc2 = {0, 0}, acc3 = {0, 0};
            #pragma unroll 2
            for (int kk = 0; kk < 25; kk++) {
                uint4 K = *(const uint4*)(KH + kk * QHSTR + hh * 8);
                float dot = MKF[s * 25 + kk];
                dot = __builtin_amdgcn_fdot2(q3, as_h2(K.w), dot, false);
                dot = __builtin_amdgcn_fdot2(q2, as_h2(K.z), dot, false);
                dot = __builtin_amdgcn_fdot2(q1, as_h2(K.y), dot, false);
                dot = __builtin_amdgcn_fdot2(q0, as_h2(K.x), dot, false);
                float p = fast_exp2(dot);
                lsum += p;
                uint4 V = *(const uint4*)(VH + kk * QHSTR + hh * 8);
                _Float16 ph = (_Float16)p;
                half2_t p2 = {ph, ph};
                acc0 += p2 * as_h2(V.x); acc1 += p2 * as_h2(V.y);
                acc2 += p2 * as_h2(V.z); acc3 += p2 * as_h2(V.w);
            }
            float inv = __builtin_amdgcn_rcpf(lsum);
            unsigned short* op = HB + s * 72 + hh * 7;
            op[0] = f2bf_t((float)acc0.x * inv); op[1] = f2bf_t((float)acc0.y * inv);
            op[2] = f2bf_t((float)acc1.x * inv); op[3] = f2bf_t((float)acc1.y * inv);
            op[4] = f2bf_t((float)acc2.x * inv); op[5] = f2bf_t((float)acc2.y * inv);
            op[6] = f2bf_t((float)acc3.x * inv);
        }
        __syncthreads();

        // ---- x += o @ Wo ----
        {
            short8 a[2][2];
            #pragma unroll
            for (int mt = 0; mt < 2; mt++)
                #pragma unroll
                for (int ks = 0; ks < 2; ks++)
                    a[mt][ks] = *(const short8*)(HB + (mt * 16 + nl) * 72 + ks * 32 + quad * 8);
            const unsigned short* bp = ws + (((size_t)(l * 4 + 3)) << 12) + (((size_t)col) << 6) + quad * 8;
            short8 b0 = *(const short8*)(bp);
            short8 b1f = *(const short8*)(bp + 32);
            f32x4 acc0 = {0, 0, 0, 0}, acc1 = {0, 0, 0, 0};
            acc0 = __builtin_amdgcn_mfma_f32_16x16x32_bf16(a[0][0], b0, acc0, 0, 0, 0);
            acc0 = __builtin_amdgcn_mfma_f32_16x16x32_bf16(a[0][1], b1f, acc0, 0, 0, 0);
            acc1 = __builtin_amdgcn_mfma_f32_16x16x32_bf16(a[1][0], b0, acc1, 0, 0, 0);
            acc1 = __builtin_amdgcn_mfma_f32_16x16x32_bf16(a[1][1], b1f, acc1, 0, 0, 0);
            if (col < 56) {
                #pragma unroll
                for (int r = 0; r < 4; r++) {
                    int row0 = quad * 4 + r;
                    XS[row0 * XSTR + col] += acc0[r];
                    int row1 = 16 + row0;
                    if (row1 < 25) XS[row1 * XSTR + col] += acc1[r];
                }
            }
        }
        __syncthreads();

        // ---- fused LN2 ----
        {
            float x[7]; float sum = 0.f, sq = 0.f;
            if (ln_s < 25) {
                const float* xp = XS + ln_s * XSTR + ln_p * 7;
                #pragma unroll
                for (int j = 0; j < 7; j++) { x[j] = xp[j]; sum += x[j]; sq += x[j] * x[j]; }
            }
            #pragma unroll
            for (int off = 1; off < 8; off <<= 1) {
                sum += __shfl_xor(sum, off, 64);
                sq  += __shfl_xor(sq,  off, 64);
            }
            if (ln_s < 25) {
                float mean = sum * (1.0f / 56.0f);
                float rs = __builtin_amdgcn_rsqf(sq * (1.0f / 56.0f) - mean * mean + 1e-5f);
                unsigned short* hp = HB + ln_s * 72 + ln_p * 7;
                #pragma unroll
                for (int j = 0; j < 7; j++) {
                    int d = ln_p * 7 + j;
                    hp[j] = f2bf_t((x[j] - mean) * rs * g2[d] + e2[d]);
                }
            }
        }
        __syncthreads();

        // ---- FFN1: f = gelu(h @ W1 + b1) -> FB (clobbers QKV-f16, dead) ----
        {
            short8 a[2][2];
            #pragma unroll
            for (int mt = 0; mt < 2; mt++)
                #pragma unroll
                for (int ks = 0; ks < 2; ks++)
                    a[mt][ks] = *(const short8*)(HB + (mt * 16 + nl) * 72 + ks * 32 + quad * 8);
            for (int u = wid; u < 14; u += 4) {
                int c1 = u * 16 + nl;
                const unsigned short* bp = w1t_all + (((size_t)(l * 224 + c1)) << 6) + quad * 8;
                short8 b0 = *(const short8*)(bp);
                short8 b1f = *(const short8*)(bp + 32);
                f32x4 acc0 = {0, 0, 0, 0}, acc1 = {0, 0, 0, 0};
                acc0 = __builtin_amdgcn_mfma_f32_16x16x32_bf16(a[0][0], b0, acc0, 0, 0, 0);
                acc0 = __builtin_amdgcn_mfma_f32_16x16x32_bf16(a[0][1], b1f, acc0, 0, 0, 0);
                acc1 = __builtin_amdgcn_mfma_f32_16x16x32_bf16(a[1][0], b0, acc1, 0, 0, 0);
                acc1 = __builtin_amdgcn_mfma_f32_16x16x32_bf16(a[1][1], b1f, acc1, 0, 0, 0);
                float bias = b1[l * 224 + c1];
                #pragma unroll
                for (int r = 0; r < 4; r++) {
                    int row0 = quad * 4 + r;
                    FB[row0 * FSTR + c1] = f2bf_t(gelu_sig(acc0[r] + bias));
                    int row1 = 16 + row0;
                    if (row1 < 25) FB[row1 * FSTR + c1] = f2bf_t(gelu_sig(acc1[r] + bias));
                }
            }
        }
        __syncthreads();

        // ---- FFN2: x += f @ W2 + b2 (K=224; out-of-range A-rows clamped to 24) ----
        {
            int r1 = 16 + nl; if (r1 > 24) r1 = 24;      // rows >=25 produce discarded C rows
            const unsigned short* a0p = FB + nl * FSTR;
            const unsigned short* a1p = FB + r1 * FSTR;
            const unsigned short* bp0 = w2t_all + ((size_t)(l * 64 + col)) * 224 + quad * 8;
            f32x4 acc0 = {0, 0, 0, 0}, acc1 = {0, 0, 0, 0};
            #pragma unroll
            for (int ks = 0; ks < 7; ks++) {
                short8 bfrag = *(const short8*)(bp0 + ks * 32);
                short8 a0 = *(const short8*)(a0p + ks * 32 + quad * 8);
                short8 a1 = *(const short8*)(a1p + ks * 32 + quad * 8);
                acc0 = __builtin_amdgcn_mfma_f32_16x16x32_bf16(a0, bfrag, acc0, 0, 0, 0);
                acc1 = __builtin_amdgcn_mfma_f32_16x16x32_bf16(a1, bfrag, acc1, 0, 0, 0);
            }
            if (col < 56) {
                float bias = b2[l * 56 + col];
                #pragma unroll
                for (int r = 0; r < 4; r++) {
                    int row0 = quad * 4 + r;
                    XS[row0 * XSTR + col] += acc0[r] + bias;
                    int row1 = 16 + row0;
                    if (row1 < 25) XS[row1 * XSTR + col] += acc1[r] + bias;
                }
            }
        }
        __syncthreads();
    }

    // ---- output ----
    for (int t = tid; t < 40; t += NTH) {
        int s = t >> 3, j = t & 7;
        out[(b * 5 + s) * 8 + j] = XS[s * XSTR + 8 + j];
    }
}

extern "C" void kernel_launch(void* const* d_in, const int* in_sizes, int n_in,
                              void* d_out, int out_size, void* d_ws, size_t ws_size,
                              hipStream_t stream) {
    const float* nodes = (const float*)d_in[0];
    const float* edges = (const float*)d_in[1];
    const float* mask  = (const float*)d_in[2];
    const int B = in_sizes[0] / 120;
    const float* W_in = (const float*)d_in[4];
    const float* b_in = (const float*)d_in[5];
    const float* W_gp = (const float*)d_in[6];
    const float* b_gp = (const float*)d_in[7];
    const float* Wq   = (const float*)d_in[8];
    const float* Wk   = (const float*)d_in[9];
    const float* Wv   = (const float*)d_in[10];
    const float* Wo   = (const float*)d_in[11];
    const float* ln1g = (const float*)d_in[12];
    const float* ln1b = (const float*)d_in[13];
    const float* ln2g = (const float*)d_in[14];
    const float* ln2b = (const float*)d_in[15];
    const float* W1   = (const float*)d_in[16];
    const float* b1   = (const float*)d_in[17];
    const float* W2   = (const float*)d_in[18];
    const float* b2   = (const float*)d_in[19];
    float* out = (float*)d_out;
    const int L = in_sizes[8] / 3136;

    unsigned short* ws16 = (unsigned short*)d_ws;
    int prep_total = L * (16384 + 14336 + 14336);
    hipLaunchKernelGGL(prep_weights, dim3((prep_total + NTH - 1) / NTH), dim3(NTH), 0, stream,
                       Wq, Wk, Wv, Wo, W1, W2, ws16, L);

    hipLaunchKernelGGL(nbody_fused, dim3(B), dim3(NTH), 0, stream,
                       nodes, edges, mask, W_in, b_in, W_gp, b_gp,
                       ln1g, ln1b, ln2g, ln2b, b1, b2, ws16, L, out);
}